// Round 17
// baseline (223.126 us; speedup 1.0000x reference)
//
#include <hip/hip_runtime.h>
#include <hip/hip_bf16.h>
#include <stdint.h>

#define BATCH 16
#define SEQ   2048
#define DK    64
#define BQ    (BATCH * SEQ)
#define MAT   ((size_t)BQ * DK)      // 2.1M elems per output matrix

typedef float  f32x4  __attribute__((ext_vector_type(4)));
typedef __bf16 bf16x8 __attribute__((ext_vector_type(8)));
typedef unsigned short u16x8 __attribute__((ext_vector_type(8)));
typedef unsigned short u16x4 __attribute__((ext_vector_type(4)));

#define MFMA16(a, b, c) __builtin_amdgcn_mfma_f32_16x16x32_bf16((a), (b), (c), 0, 0, 0)

// ws tile block per (bh, tile): 16384 u16 = 32KB:
//   [Kr 64x64][Kp 64x64][Vr^T 64x64][Vp^T 64x64], all chunk-swizzled for LDS.
#define TILEU 16384

// Q pre-scale: 0.125 (temperature) * log2(e) -> scores emerge in log-2 domain;
// the exponential is then a BARE v_exp_f32 (no per-exp v_mul).
#define QSCALE 0.1803368756f

#if __has_builtin(__builtin_amdgcn_exp2f)
#define EXP2(x) __builtin_amdgcn_exp2f(x)
#else
#define EXP2(x) exp2f(x)
#endif

__device__ __forceinline__ unsigned short bfbits(float f) {
  return __builtin_bit_cast(unsigned short, __float2bfloat16(f));
}

__device__ __forceinline__ void cvt_store(unsigned short* dst, f32x4 a, f32x4 c) {
  u16x8 v;
  v[0] = bfbits(a[0]); v[1] = bfbits(a[1]); v[2] = bfbits(a[2]); v[3] = bfbits(a[3]);
  v[4] = bfbits(c[0]); v[5] = bfbits(c[1]); v[6] = bfbits(c[2]); v[7] = bfbits(c[3]);
  *(u16x8*)dst = v;
}

__device__ __forceinline__ bf16x8 ldbf(const unsigned short* p) {
  return __builtin_bit_cast(bf16x8, *(const u16x8*)p);
}

// async global(16B/lane) -> LDS; dest = wave-uniform base + lane*16
__device__ __forceinline__ void gload16(const unsigned short* g, unsigned short* l) {
  __builtin_amdgcn_global_load_lds(
      (const __attribute__((address_space(1))) void*)g,
      (__attribute__((address_space(3))) void*)l, 16, 0, 0);
}

// -------- Kernel 0: K/V -> bf16 swizzled tiles; Q -> bf16 rows (merged) --------
__global__ __launch_bounds__(256)
void ck_prep(const float* __restrict__ kr, const float* __restrict__ kp,
             const float* __restrict__ vr, const float* __restrict__ vp,
             const float* __restrict__ qr, const float* __restrict__ qp,
             unsigned short* __restrict__ kv, unsigned short* __restrict__ qb)
{
  __shared__ __align__(16) unsigned short VL[8192];  // Vr(4096) Vp(4096)
  const int tid = threadIdx.x;

  if (blockIdx.x >= BATCH * 32) {  // ---- Q conversion: 8 elems/thread ----
    const size_t i8 = ((size_t)(blockIdx.x - BATCH * 32) * 256 + tid) * 8;
    const float* src = (i8 < MAT) ? qr : qp;
    const size_t off = (i8 < MAT) ? i8 : i8 - MAT;
    f32x4 a = *(const f32x4*)(src + off);
    f32x4 c = *(const f32x4*)(src + off + 4);
    cvt_store(qb + i8, a * QSCALE, c * QSCALE);
    return;
  }

  const int b = blockIdx.x >> 5, tile = blockIdx.x & 31;
  unsigned short* blk = kv + (size_t)(b * 32 + tile) * TILEU;
  const size_t go = ((size_t)b * SEQ + tile * 64) * DK;

  { // K: each thread one row x 16 cols
    const int row = tid >> 2, cp = tid & 3, sw = row & 7;
    const int c0 = cp * 2, c1 = cp * 2 + 1;
    const float* gr = kr + go + (size_t)row * DK + cp * 16;
    f32x4 r0 = ((const f32x4*)gr)[0], r1 = ((const f32x4*)gr)[1];
    f32x4 r2 = ((const f32x4*)gr)[2], r3 = ((const f32x4*)gr)[3];
    const float* gp = kp + go + (size_t)row * DK + cp * 16;
    f32x4 p0 = ((const f32x4*)gp)[0], p1 = ((const f32x4*)gp)[1];
    f32x4 p2 = ((const f32x4*)gp)[2], p3 = ((const f32x4*)gp)[3];
    cvt_store(blk + row * 64 + (c0 ^ sw) * 8, r0, r1);
    cvt_store(blk + row * 64 + (c1 ^ sw) * 8, r2, r3);
    cvt_store(blk + 4096 + row * 64 + (c0 ^ sw) * 8, p0, p1);
    cvt_store(blk + 4096 + row * 64 + (c1 ^ sw) * 8, p2, p3);
  }
  { // V: transpose+swizzle through LDS
    const int key = tid & 15, d0 = (tid >> 4) * 4;
    #pragma unroll
    for (int pass = 0; pass < 4; ++pass) {
      const int kk = pass * 16 + key;
      f32x4 a = *(const f32x4*)(vr + go + (size_t)kk * DK + d0);
      f32x4 c = *(const f32x4*)(vp + go + (size_t)kk * DK + d0);
      const int kc = kk >> 3, kl = kk & 7;
      #pragma unroll
      for (int j = 0; j < 4; ++j) {
        const int d = d0 + j;
        VL[d * 64 + (kc ^ (d & 7)) * 8 + kl]        = bfbits(a[j]);
        VL[4096 + d * 64 + (kc ^ (d & 7)) * 8 + kl] = bfbits(c[j]);
      }
    }
  }
  __syncthreads();
  #pragma unroll
  for (int it = 0; it < 4; ++it)  // linear coalesced dump LDS -> ws
    *(u16x8*)(blk + 8192 + it * 2048 + tid * 8) = *(const u16x8*)(VL + it * 2048 + tid * 8);
}

// ---------------- Kernel 1: partial row sums (pipelined) ----------------
// One block = 64 q-rows x one 512-key slice. 2048 blocks, 32KB LDS (double
// buffer) -> 5 blocks/CU, 20 waves/CU. Counted vmcnt(4): next tile's loads
// stay in flight across both barriers. No max-subtraction: |S|/8 <~ 6.
__global__ __launch_bounds__(256, 4)
void ck_sums(const unsigned short* __restrict__ qb,
             const unsigned short* __restrict__ kv, float* __restrict__ wsums)
{
  __shared__ __align__(16) unsigned short KT[2][8192];  // per buf: Kr(4096) Kp(4096)

  const int tid  = threadIdx.x;
  const int wq   = tid >> 6, lane = tid & 63;
  const int lrow = lane & 15, lgrp = lane >> 4;

  const int hw = blockIdx.x;                       // XCD swizzle (2048 = 8*256)
  const int logical = (hw & 7) * 256 + (hw >> 3);
  const int b = logical >> 7, qtile = (logical >> 2) & 31, slice = logical & 3;

  const int qrow = qtile * 64 + wq * 16 + lrow;
  const size_t qoff = ((size_t)b * SEQ + qrow) * DK;
  bf16x8 aQ0 = ldbf(qb + qoff + lgrp * 8);
  bf16x8 aQ1 = ldbf(qb + qoff + 32 + lgrp * 8);
  bf16x8 aQ2 = ldbf(qb + MAT + qoff + lgrp * 8);
  bf16x8 aQ3 = ldbf(qb + MAT + qoff + 32 + lgrp * 8);

  auto issue = [&](int tile, int buf) {
    const unsigned short* src = kv + (size_t)(b * 32 + tile) * TILEU;  // K at +0
    #pragma unroll
    for (int c = 0; c < 4; ++c) {   // 16KB = 16 x 1KB chunks, 4 per wave
      const int ch = wq * 4 + c;
      gload16(src + ch * 512 + lane * 8, &KT[buf][ch * 512]);
    }
  };

  float lsR[4] = {0.f, 0.f, 0.f, 0.f};
  float lsP[4] = {0.f, 0.f, 0.f, 0.f};

  issue(slice * 8 + 0, 0);
  issue(slice * 8 + 1, 1);
  int cur = 0;
  for (int i = 0; i < 8; ++i) {
    if (i < 7) { asm volatile("s_waitcnt vmcnt(4)" ::: "memory"); }  // next tile stays in flight
    else       { asm volatile("s_waitcnt vmcnt(0)" ::: "memory"); }
    __builtin_amdgcn_sched_barrier(0);
    __syncthreads();                 // whole tile visible (each wave waited its own)

    const unsigned short* KB = KT[cur];
    #pragma unroll
    for (int t = 0; t < 4; ++t) {
      const int key16 = t * 16 + lrow;
      const int swk = lrow & 7;
      bf16x8 b0 = ldbf(&KB[key16 * 64 + ((lgrp    ) ^ swk) * 8]);
      bf16x8 b1 = ldbf(&KB[key16 * 64 + ((lgrp + 4) ^ swk) * 8]);
      bf16x8 b2 = ldbf(&KB[4096 + key16 * 64 + ((lgrp    ) ^ swk) * 8]);
      bf16x8 b3 = ldbf(&KB[4096 + key16 * 64 + ((lgrp + 4) ^ swk) * 8]);
      f32x4 t1 = {}, t2 = {}, sp = {};
      t1 = MFMA16(aQ0, b0, t1); t1 = MFMA16(aQ1, b1, t1);  // q_r.k_r
      t2 = MFMA16(aQ2, b2, t2); t2 = MFMA16(aQ3, b3, t2);  // q_p.k_p
      sp = MFMA16(aQ0, b2, sp); sp = MFMA16(aQ1, b3, sp);  // q_r.k_p
      sp = MFMA16(aQ2, b0, sp); sp = MFMA16(aQ3, b1, sp);  // q_p.k_r
      #pragma unroll
      for (int r = 0; r < 4; ++r) {
        lsR[r] += EXP2(t1[r] - t2[r]);   // log2-domain scores (Q pre-scaled)
        lsP[r] += EXP2(sp[r]);
      }
    }
    __syncthreads();                 // all waves done reading KT[cur]
    if (i + 2 < 8) issue(slice * 8 + i + 2, cur);
    cur ^= 1;
  }

  #pragma unroll
  for (int r = 0; r < 4; ++r) {
    float sR = lsR[r], sP = lsP[r];
    #pragma unroll
    for (int m = 1; m < 16; m <<= 1) {
      sR += __shfl_xor(sR, m, 64);
      sP += __shfl_xor(sP, m, 64);
    }
    if (lrow == 0) {
      const size_t row = (size_t)b * SEQ + qtile * 64 + wq * 16 + lgrp * 4 + r;
      wsums[(size_t)(slice * 2 + 0) * BQ + row] = sR;
      wsums[(size_t)(slice * 2 + 1) * BQ + row] = sP;
    }
  }
}

// ---------------- Kernel 2: PV + normalized attn (full key range) ----------------
// One block = 64 q-rows x ALL 2048 keys; 512 blocks, LDS 72KB (double-buffered
// KV + P panels) -> 2 blocks/CU. vmcnt ledger: per wave per tile = 8 loads +
// 4 NT stores; steady-state wait vmcnt(12) = stores(i-1) 4 + loads(i+1) 8,
// so attn stores never gate compute. (R11/R15 structure, 146.97us reference.)
__global__ __launch_bounds__(256, 2)
void ck_main(const unsigned short* __restrict__ qb,
             const unsigned short* __restrict__ kv,
             const float* __restrict__ wsums, float* __restrict__ dout)
{
  __shared__ __align__(16) unsigned short KV[2][16384];   // 64KB: Kr,Kp,Vr,Vp x2
  __shared__ __align__(16) unsigned short Pr[64][32], Pp[64][32];

  const int tid  = threadIdx.x;
  const int wq   = tid >> 6, lane = tid & 63;
  const int lrow = lane & 15, lgrp = lane >> 4;

  const int hw = blockIdx.x;                       // XCD swizzle (512 = 8*64)
  const int logical = (hw & 7) * 64 + (hw >> 3);
  const int b = logical >> 5, qtile = logical & 31;

  float* outR = dout;
  float* outP = dout + MAT;
  float* attn = dout + 2 * MAT + ((size_t)b * SEQ + (size_t)qtile * 64) * SEQ;

  const int qrow = qtile * 64 + wq * 16 + lrow;
  const size_t qoff = ((size_t)b * SEQ + qrow) * DK;
  bf16x8 aQ0 = ldbf(qb + qoff + lgrp * 8);
  bf16x8 aQ1 = ldbf(qb + qoff + 32 + lgrp * 8);
  bf16x8 aQ2 = ldbf(qb + MAT + qoff + lgrp * 8);
  bf16x8 aQ3 = ldbf(qb + MAT + qoff + 32 + lgrp * 8);

  const int qloc = wq * 16 + lgrp * 4;
  float iR[4], iP[4];
  {
    const size_t base = (size_t)b * SEQ + qtile * 64 + qloc;
    #pragma unroll
    for (int r = 0; r < 4; ++r) {
      float sR = 0.f, sP = 0.f;
      #pragma unroll
      for (int z = 0; z < 4; ++z) {
        sR += wsums[(size_t)(z * 2 + 0) * BQ + base + r];
        sP += wsums[(size_t)(z * 2 + 1) * BQ + base + r];
      }
      iR[r] = 1.0f / sR;
      iP[r] = 1.0f / sP;
    }
  }

  auto issue = [&](int tile, int buf) {
    const unsigned short* src = kv + (size_t)(b * 32 + tile) * TILEU;
    #pragma unroll
    for (int c = 0; c < 8; ++c) {   // 32KB = 32 x 1KB chunks, 8 per wave
      const int ch = wq * 8 + c;
      gload16(src + ch * 512 + lane * 8, &KV[buf][ch * 512]);
    }
  };

  const u16x8 SGN = {0x8000, 0x8000, 0x8000, 0x8000, 0x8000, 0x8000, 0x8000, 0x8000};
  f32x4 accR[4] = {}, accP[4] = {};

  issue(0, 0);
  issue(1, 1);
  int cur = 0;
  for (int i = 0; i < 32; ++i) {
    const int k0 = i * 64;
    // vmcnt ledger: newer-than-tile-i's-loads = stores(i-1)[4] + loads(i+1)[8]
    if (i == 0)      { asm volatile("s_waitcnt vmcnt(8)"  ::: "memory"); }
    else if (i < 31) { asm volatile("s_waitcnt vmcnt(12)" ::: "memory"); }
    else             { asm volatile("s_waitcnt vmcnt(4)"  ::: "memory"); }
    __builtin_amdgcn_sched_barrier(0);
    __syncthreads();

    const unsigned short* KB = KV[cur];
    #pragma unroll
    for (int h = 0; h < 2; ++h) {
      #pragma unroll
      for (int t = 0; t < 2; ++t) {
        const int key16 = (h * 2 + t) * 16 + lrow;
        const int swk = lrow & 7;
        bf16x8 b0 = ldbf(&KB[key16 * 64 + ((lgrp    ) ^ swk) * 8]);
        bf16x8 b1 = ldbf(&KB[key16 * 64 + ((lgrp + 4) ^ swk) * 8]);
        bf16x8 b2 = ldbf(&KB[4096 + key16 * 64 + ((lgrp    ) ^ swk) * 8]);
        bf16x8 b3 = ldbf(&KB[4096 + key16 * 64 + ((lgrp + 4) ^ swk) * 8]);
        f32x4 t1 = {}, t2 = {}, sp = {};
        t1 = MFMA16(aQ0, b0, t1); t1 = MFMA16(aQ1, b1, t1);
        t2 = MFMA16(aQ2, b2, t2); t2 = MFMA16(aQ3, b3, t2);
        sp = MFMA16(aQ0, b2, sp); sp = MFMA16(aQ1, b3, sp);
        sp = MFMA16(aQ2, b0, sp); sp = MFMA16(aQ3, b1, sp);
        #pragma unroll
        for (int r = 0; r < 4; ++r) {
          const float er = EXP2(t1[r] - t2[r]) * iR[r];   // log2-domain scores
          const float ep = EXP2(sp[r]) * iP[r];
          const int row = qloc + r, col = t * 16 + lrow;
          const int pc = ((col >> 3) ^ (row & 3)) * 8 + (col & 7);
          Pr[row][pc] = bfbits(er);   // wave-private rows: no barrier
          Pp[row][pc] = bfbits(ep);
        }
      }
      { // PV: accR += Pr.Vr + (-Pp).Vp ; accP += Pr.Vp + Pp.Vr
        const int prow = wq * 16 + lrow;
        u16x8 uar = *(const u16x8*)&Pr[prow][(lgrp ^ (prow & 3)) * 8];
        u16x8 uap = *(const u16x8*)&Pp[prow][(lgrp ^ (prow & 3)) * 8];
        u16x8 uan = uap ^ SGN;
        bf16x8 apr = __builtin_bit_cast(bf16x8, uar);
        bf16x8 app = __builtin_bit_cast(bf16x8, uap);
        bf16x8 apn = __builtin_bit_cast(bf16x8, uan);
        #pragma unroll
        for (int nt = 0; nt < 4; ++nt) {
          const int d = nt * 16 + lrow;
          const int cv = ((h * 4 + lgrp) ^ (d & 7)) * 8;
          bf16x8 bvr = ldbf(&KB[8192  + d * 64 + cv]);
          bf16x8 bvp = ldbf(&KB[12288 + d * 64 + cv]);
          accR[nt] = MFMA16(apr, bvr, accR[nt]);
          accR[nt] = MFMA16(apn, bvp, accR[nt]);
          accP[nt] = MFMA16(apr, bvp, accP[nt]);
          accP[nt] = MFMA16(app, bvr, accP[nt]);
        }
      }
      { // attn write: full 128B lines (8 lanes x 16B per row), NT
        const int j8 = lane & 7;
        #pragma unroll
        for (int s = 0; s < 2; ++s) {
          const int arow = wq * 16 + s * 8 + (lane >> 3);
          const int pc = (((j8 >> 1) ^ (arow & 3)) * 8) + (j8 & 1) * 4;
          u16x4 ua = *(const u16x4*)&Pr[arow][pc];
          f32x4 fa;
          #pragma unroll
          for (int q = 0; q < 4; ++q)
            fa[q] = __builtin_bit_cast(float, (unsigned)ua[q] << 16);
          float* dst = attn + (size_t)arow * SEQ + k0 + h * 32 + j8 * 4;
          __builtin_nontemporal_store(fa, (f32x4*)dst);
        }
      }
    }
    __syncthreads();                 // all waves done reading KV[cur]
    if (i + 2 < 32) issue(i + 2, cur);
    cur ^= 1;
  }

  // ---- O complete per block: direct store ----
  #pragma unroll
  for (int nt = 0; nt < 4; ++nt) {
    const int d = nt * 16 + lrow;
    #pragma unroll
    for (int r = 0; r < 4; ++r) {
      const size_t o = ((size_t)b * SEQ + qtile * 64 + qloc + r) * DK + d;
      outR[o] = accR[nt][r];
      outP[o] = accP[nt][r];
    }
  }
}

extern "C" void kernel_launch(void* const* d_in, const int* in_sizes, int n_in,
                              void* d_out, int out_size, void* d_ws, size_t ws_size,
                              hipStream_t stream)
{
  const float* qr = (const float*)d_in[0];
  const float* kr = (const float*)d_in[1];
  const float* vr = (const float*)d_in[2];
  const float* qp = (const float*)d_in[3];
  const float* kp = (const float*)d_in[4];
  const float* vp = (const float*)d_in[5];
  float* out = (float*)d_out;

  // ws: [kv bf16 tiles 16MB][qb bf16 8MB][wsums 1MB]
  unsigned short* kv = (unsigned short*)d_ws;
  unsigned short* qb = (unsigned short*)((char*)d_ws + (16u << 20));
  float* wsums = (float*)((char*)d_ws + (24u << 20));

  const unsigned qblocks = (unsigned)(2 * MAT / 8 / 256);
  ck_prep<<<BATCH * 32 + qblocks, 256, 0, stream>>>(kr, kp, vr, vp, qr, qp, kv, qb);
  ck_sums<<<4 * 32 * BATCH, 256, 0, stream>>>(qb, kv, wsums);
  ck_main<<<32 * BATCH, 256, 0, stream>>>(qb, kv, wsums, out);
}

// Round 18
// 146.222 us; speedup vs baseline: 1.5259x; 1.5259x over previous
//
#include <hip/hip_runtime.h>
#include <hip/hip_bf16.h>
#include <stdint.h>

#define BATCH 16
#define SEQ   2048
#define DK    64
#define BQ    (BATCH * SEQ)
#define MAT   ((size_t)BQ * DK)      // 2.1M elems per output matrix

typedef float  f32x4  __attribute__((ext_vector_type(4)));
typedef __bf16 bf16x8 __attribute__((ext_vector_type(8)));
typedef unsigned short u16x8 __attribute__((ext_vector_type(8)));
typedef unsigned short u16x4 __attribute__((ext_vector_type(4)));

#define MFMA16(a, b, c) __builtin_amdgcn_mfma_f32_16x16x32_bf16((a), (b), (c), 0, 0, 0)

// ws tile block per (bh, tile): 16384 u16 = 32KB:
//   [Kr 64x64][Kp 64x64][Vr^T 64x64][Vp^T 64x64], all chunk-swizzled for LDS.
#define TILEU 16384

__device__ __forceinline__ unsigned short bfbits(float f) {
  return __builtin_bit_cast(unsigned short, __float2bfloat16(f));
}

__device__ __forceinline__ void cvt_store(unsigned short* dst, f32x4 a, f32x4 c) {
  u16x8 v;
  v[0] = bfbits(a[0]); v[1] = bfbits(a[1]); v[2] = bfbits(a[2]); v[3] = bfbits(a[3]);
  v[4] = bfbits(c[0]); v[5] = bfbits(c[1]); v[6] = bfbits(c[2]); v[7] = bfbits(c[3]);
  *(u16x8*)dst = v;
}

__device__ __forceinline__ bf16x8 ldbf(const unsigned short* p) {
  return __builtin_bit_cast(bf16x8, *(const u16x8*)p);
}

// async global(16B/lane) -> LDS; dest = wave-uniform base + lane*16
__device__ __forceinline__ void gload16(const unsigned short* g, unsigned short* l) {
  __builtin_amdgcn_global_load_lds(
      (const __attribute__((address_space(1))) void*)g,
      (__attribute__((address_space(3))) void*)l, 16, 0, 0);
}

// -------- Kernel 0: K/V -> bf16 swizzled tiles; Q -> bf16 rows (merged) --------
// Q is PRE-SCALED by 0.125 (temperature) — exact in bf16 (exponent shift);
// removes the per-score multiply in ck_sums and ck_main.
__global__ __launch_bounds__(256)
void ck_prep(const float* __restrict__ kr, const float* __restrict__ kp,
             const float* __restrict__ vr, const float* __restrict__ vp,
             const float* __restrict__ qr, const float* __restrict__ qp,
             unsigned short* __restrict__ kv, unsigned short* __restrict__ qb)
{
  __shared__ __align__(16) unsigned short VL[8192];  // Vr(4096) Vp(4096)
  const int tid = threadIdx.x;

  if (blockIdx.x >= BATCH * 32) {  // ---- Q conversion: 8 elems/thread ----
    const size_t i8 = ((size_t)(blockIdx.x - BATCH * 32) * 256 + tid) * 8;
    const float* src = (i8 < MAT) ? qr : qp;
    const size_t off = (i8 < MAT) ? i8 : i8 - MAT;
    f32x4 a = *(const f32x4*)(src + off);
    f32x4 c = *(const f32x4*)(src + off + 4);
    cvt_store(qb + i8, a * 0.125f, c * 0.125f);
    return;
  }

  const int b = blockIdx.x >> 5, tile = blockIdx.x & 31;
  unsigned short* blk = kv + (size_t)(b * 32 + tile) * TILEU;
  const size_t go = ((size_t)b * SEQ + tile * 64) * DK;

  { // K: each thread one row x 16 cols
    const int row = tid >> 2, cp = tid & 3, sw = row & 7;
    const int c0 = cp * 2, c1 = cp * 2 + 1;
    const float* gr = kr + go + (size_t)row * DK + cp * 16;
    f32x4 r0 = ((const f32x4*)gr)[0], r1 = ((const f32x4*)gr)[1];
    f32x4 r2 = ((const f32x4*)gr)[2], r3 = ((const f32x4*)gr)[3];
    const float* gp = kp + go + (size_t)row * DK + cp * 16;
    f32x4 p0 = ((const f32x4*)gp)[0], p1 = ((const f32x4*)gp)[1];
    f32x4 p2 = ((const f32x4*)gp)[2], p3 = ((const f32x4*)gp)[3];
    cvt_store(blk + row * 64 + (c0 ^ sw) * 8, r0, r1);
    cvt_store(blk + row * 64 + (c1 ^ sw) * 8, r2, r3);
    cvt_store(blk + 4096 + row * 64 + (c0 ^ sw) * 8, p0, p1);
    cvt_store(blk + 4096 + row * 64 + (c1 ^ sw) * 8, p2, p3);
  }
  { // V: transpose+swizzle through LDS
    const int key = tid & 15, d0 = (tid >> 4) * 4;
    #pragma unroll
    for (int pass = 0; pass < 4; ++pass) {
      const int kk = pass * 16 + key;
      f32x4 a = *(const f32x4*)(vr + go + (size_t)kk * DK + d0);
      f32x4 c = *(const f32x4*)(vp + go + (size_t)kk * DK + d0);
      const int kc = kk >> 3, kl = kk & 7;
      #pragma unroll
      for (int j = 0; j < 4; ++j) {
        const int d = d0 + j;
        VL[d * 64 + (kc ^ (d & 7)) * 8 + kl]        = bfbits(a[j]);
        VL[4096 + d * 64 + (kc ^ (d & 7)) * 8 + kl] = bfbits(c[j]);
      }
    }
  }
  __syncthreads();
  #pragma unroll
  for (int it = 0; it < 4; ++it)  // linear coalesced dump LDS -> ws
    *(u16x8*)(blk + 8192 + it * 2048 + tid * 8) = *(const u16x8*)(VL + it * 2048 + tid * 8);
}

// ---------------- Kernel 1: partial row sums (pipelined) ----------------
// One block = 64 q-rows x one 512-key slice. 2048 blocks, 32KB LDS (double
// buffer) -> 5 blocks/CU, 20 waves/CU. Counted vmcnt(4): next tile's loads
// stay in flight across both barriers. No max-subtraction: |S|/8 <~ 6.
__global__ __launch_bounds__(256, 4)
void ck_sums(const unsigned short* __restrict__ qb,
             const unsigned short* __restrict__ kv, float* __restrict__ wsums)
{
  __shared__ __align__(16) unsigned short KT[2][8192];  // per buf: Kr(4096) Kp(4096)

  const int tid  = threadIdx.x;
  const int wq   = tid >> 6, lane = tid & 63;
  const int lrow = lane & 15, lgrp = lane >> 4;

  const int hw = blockIdx.x;                       // XCD swizzle (2048 = 8*256)
  const int logical = (hw & 7) * 256 + (hw >> 3);
  const int b = logical >> 7, qtile = (logical >> 2) & 31, slice = logical & 3;

  const int qrow = qtile * 64 + wq * 16 + lrow;
  const size_t qoff = ((size_t)b * SEQ + qrow) * DK;
  bf16x8 aQ0 = ldbf(qb + qoff + lgrp * 8);
  bf16x8 aQ1 = ldbf(qb + qoff + 32 + lgrp * 8);
  bf16x8 aQ2 = ldbf(qb + MAT + qoff + lgrp * 8);
  bf16x8 aQ3 = ldbf(qb + MAT + qoff + 32 + lgrp * 8);

  auto issue = [&](int tile, int buf) {
    const unsigned short* src = kv + (size_t)(b * 32 + tile) * TILEU;  // K at +0
    #pragma unroll
    for (int c = 0; c < 4; ++c) {   // 16KB = 16 x 1KB chunks, 4 per wave
      const int ch = wq * 4 + c;
      gload16(src + ch * 512 + lane * 8, &KT[buf][ch * 512]);
    }
  };

  float lsR[4] = {0.f, 0.f, 0.f, 0.f};
  float lsP[4] = {0.f, 0.f, 0.f, 0.f};

  issue(slice * 8 + 0, 0);
  issue(slice * 8 + 1, 1);
  int cur = 0;
  for (int i = 0; i < 8; ++i) {
    if (i < 7) { asm volatile("s_waitcnt vmcnt(4)" ::: "memory"); }  // next tile stays in flight
    else       { asm volatile("s_waitcnt vmcnt(0)" ::: "memory"); }
    __builtin_amdgcn_sched_barrier(0);
    __syncthreads();                 // whole tile visible (each wave waited its own)

    const unsigned short* KB = KT[cur];
    #pragma unroll
    for (int t = 0; t < 4; ++t) {
      const int key16 = t * 16 + lrow;
      const int swk = lrow & 7;
      bf16x8 b0 = ldbf(&KB[key16 * 64 + ((lgrp    ) ^ swk) * 8]);
      bf16x8 b1 = ldbf(&KB[key16 * 64 + ((lgrp + 4) ^ swk) * 8]);
      bf16x8 b2 = ldbf(&KB[4096 + key16 * 64 + ((lgrp    ) ^ swk) * 8]);
      bf16x8 b3 = ldbf(&KB[4096 + key16 * 64 + ((lgrp + 4) ^ swk) * 8]);
      f32x4 t1 = {}, t2 = {}, sp = {};
      t1 = MFMA16(aQ0, b0, t1); t1 = MFMA16(aQ1, b1, t1);  // q_r.k_r
      t2 = MFMA16(aQ2, b2, t2); t2 = MFMA16(aQ3, b3, t2);  // q_p.k_p
      sp = MFMA16(aQ0, b2, sp); sp = MFMA16(aQ1, b3, sp);  // q_r.k_p
      sp = MFMA16(aQ2, b0, sp); sp = MFMA16(aQ3, b1, sp);  // q_p.k_r
      #pragma unroll
      for (int r = 0; r < 4; ++r) {
        lsR[r] += __expf(t1[r] - t2[r]);   // Q pre-scaled by 1/8
        lsP[r] += __expf(sp[r]);
      }
    }
    __syncthreads();                 // all waves done reading KT[cur]
    if (i + 2 < 8) issue(slice * 8 + i + 2, cur);
    cur ^= 1;
  }

  #pragma unroll
  for (int r = 0; r < 4; ++r) {
    float sR = lsR[r], sP = lsP[r];
    #pragma unroll
    for (int m = 1; m < 16; m <<= 1) {
      sR += __shfl_xor(sR, m, 64);
      sP += __shfl_xor(sP, m, 64);
    }
    if (lrow == 0) {
      const size_t row = (size_t)b * SEQ + qtile * 64 + wq * 16 + lgrp * 4 + r;
      wsums[(size_t)(slice * 2 + 0) * BQ + row] = sR;
      wsums[(size_t)(slice * 2 + 1) * BQ + row] = sP;
    }
  }
}

// ---------------- Kernel 2: PV + normalized attn (full key range) ----------------
// One block = 64 q-rows x ALL 2048 keys; 512 blocks, LDS 72KB (double-buffered
// KV + P panels) -> 2 blocks/CU. vmcnt ledger: per wave per tile = 8 loads +
// 4 NT stores; steady-state wait vmcnt(12) = stores(i-1) 4 + loads(i+1) 8,
// so attn stores never gate compute. (R11 structure, 146.97us reference.)
__global__ __launch_bounds__(256, 2)
void ck_main(const unsigned short* __restrict__ qb,
             const unsigned short* __restrict__ kv,
             const float* __restrict__ wsums, float* __restrict__ dout)
{
  __shared__ __align__(16) unsigned short KV[2][16384];   // 64KB: Kr,Kp,Vr,Vp x2
  __shared__ __align__(16) unsigned short Pr[64][32], Pp[64][32];

  const int tid  = threadIdx.x;
  const int wq   = tid >> 6, lane = tid & 63;
  const int lrow = lane & 15, lgrp = lane >> 4;

  const int hw = blockIdx.x;                       // XCD swizzle (512 = 8*64)
  const int logical = (hw & 7) * 64 + (hw >> 3);
  const int b = logical >> 5, qtile = logical & 31;

  float* outR = dout;
  float* outP = dout + MAT;
  float* attn = dout + 2 * MAT + ((size_t)b * SEQ + (size_t)qtile * 64) * SEQ;

  const int qrow = qtile * 64 + wq * 16 + lrow;
  const size_t qoff = ((size_t)b * SEQ + qrow) * DK;
  bf16x8 aQ0 = ldbf(qb + qoff + lgrp * 8);
  bf16x8 aQ1 = ldbf(qb + qoff + 32 + lgrp * 8);
  bf16x8 aQ2 = ldbf(qb + MAT + qoff + lgrp * 8);
  bf16x8 aQ3 = ldbf(qb + MAT + qoff + 32 + lgrp * 8);

  const int qloc = wq * 16 + lgrp * 4;
  float iR[4], iP[4];
  {
    const size_t base = (size_t)b * SEQ + qtile * 64 + qloc;
    #pragma unroll
    for (int r = 0; r < 4; ++r) {
      float sR = 0.f, sP = 0.f;
      #pragma unroll
      for (int z = 0; z < 4; ++z) {
        sR += wsums[(size_t)(z * 2 + 0) * BQ + base + r];
        sP += wsums[(size_t)(z * 2 + 1) * BQ + base + r];
      }
      iR[r] = 1.0f / sR;
      iP[r] = 1.0f / sP;
    }
  }

  auto issue = [&](int tile, int buf) {
    const unsigned short* src = kv + (size_t)(b * 32 + tile) * TILEU;
    #pragma unroll
    for (int c = 0; c < 8; ++c) {   // 32KB = 32 x 1KB chunks, 8 per wave
      const int ch = wq * 8 + c;
      gload16(src + ch * 512 + lane * 8, &KV[buf][ch * 512]);
    }
  };

  const u16x8 SGN = {0x8000, 0x8000, 0x8000, 0x8000, 0x8000, 0x8000, 0x8000, 0x8000};
  f32x4 accR[4] = {}, accP[4] = {};

  issue(0, 0);
  issue(1, 1);
  int cur = 0;
  for (int i = 0; i < 32; ++i) {
    const int k0 = i * 64;
    // vmcnt ledger: newer-than-tile-i's-loads = stores(i-1)[4] + loads(i+1)[8]
    if (i == 0)      { asm volatile("s_waitcnt vmcnt(8)"  ::: "memory"); }
    else if (i < 31) { asm volatile("s_waitcnt vmcnt(12)" ::: "memory"); }
    else             { asm volatile("s_waitcnt vmcnt(4)"  ::: "memory"); }
    __builtin_amdgcn_sched_barrier(0);
    __syncthreads();

    const unsigned short* KB = KV[cur];
    #pragma unroll
    for (int h = 0; h < 2; ++h) {
      #pragma unroll
      for (int t = 0; t < 2; ++t) {
        const int key16 = (h * 2 + t) * 16 + lrow;
        const int swk = lrow & 7;
        bf16x8 b0 = ldbf(&KB[key16 * 64 + ((lgrp    ) ^ swk) * 8]);
        bf16x8 b1 = ldbf(&KB[key16 * 64 + ((lgrp + 4) ^ swk) * 8]);
        bf16x8 b2 = ldbf(&KB[4096 + key16 * 64 + ((lgrp    ) ^ swk) * 8]);
        bf16x8 b3 = ldbf(&KB[4096 + key16 * 64 + ((lgrp + 4) ^ swk) * 8]);
        f32x4 t1 = {}, t2 = {}, sp = {};
        t1 = MFMA16(aQ0, b0, t1); t1 = MFMA16(aQ1, b1, t1);
        t2 = MFMA16(aQ2, b2, t2); t2 = MFMA16(aQ3, b3, t2);
        sp = MFMA16(aQ0, b2, sp); sp = MFMA16(aQ1, b3, sp);
        sp = MFMA16(aQ2, b0, sp); sp = MFMA16(aQ3, b1, sp);
        #pragma unroll
        for (int r = 0; r < 4; ++r) {
          const float er = __expf(t1[r] - t2[r]) * iR[r];   // Q pre-scaled by 1/8
          const float ep = __expf(sp[r]) * iP[r];
          const int row = qloc + r, col = t * 16 + lrow;
          const int pc = ((col >> 3) ^ (row & 3)) * 8 + (col & 7);
          Pr[row][pc] = bfbits(er);   // wave-private rows: no barrier
          Pp[row][pc] = bfbits(ep);
        }
      }
      { // PV: accR += Pr.Vr + (-Pp).Vp ; accP += Pr.Vp + Pp.Vr
        const int prow = wq * 16 + lrow;
        u16x8 uar = *(const u16x8*)&Pr[prow][(lgrp ^ (prow & 3)) * 8];
        u16x8 uap = *(const u16x8*)&Pp[prow][(lgrp ^ (prow & 3)) * 8];
        u16x8 uan = uap ^ SGN;
        bf16x8 apr = __builtin_bit_cast(bf16x8, uar);
        bf16x8 app = __builtin_bit_cast(bf16x8, uap);
        bf16x8 apn = __builtin_bit_cast(bf16x8, uan);
        #pragma unroll
        for (int nt = 0; nt < 4; ++nt) {
          const int d = nt * 16 + lrow;
          const int cv = ((h * 4 + lgrp) ^ (d & 7)) * 8;
          bf16x8 bvr = ldbf(&KB[8192  + d * 64 + cv]);
          bf16x8 bvp = ldbf(&KB[12288 + d * 64 + cv]);
          accR[nt] = MFMA16(apr, bvr, accR[nt]);
          accR[nt] = MFMA16(apn, bvp, accR[nt]);
          accP[nt] = MFMA16(apr, bvp, accP[nt]);
          accP[nt] = MFMA16(app, bvr, accP[nt]);
        }
      }
      { // attn write: full 128B lines (8 lanes x 16B per row), NT
        const int j8 = lane & 7;
        #pragma unroll
        for (int s = 0; s < 2; ++s) {
          const int arow = wq * 16 + s * 8 + (lane >> 3);
          const int pc = (((j8 >> 1) ^ (arow & 3)) * 8) + (j8 & 1) * 4;
          u16x4 ua = *(const u16x4*)&Pr[arow][pc];
          f32x4 fa;
          #pragma unroll
          for (int q = 0; q < 4; ++q)
            fa[q] = __builtin_bit_cast(float, (unsigned)ua[q] << 16);
          float* dst = attn + (size_t)arow * SEQ + k0 + h * 32 + j8 * 4;
          __builtin_nontemporal_store(fa, (f32x4*)dst);
        }
      }
    }
    __syncthreads();                 // all waves done reading KV[cur]
    if (i + 2 < 32) issue(i + 2, cur);
    cur ^= 1;
  }

  // ---- O complete per block: direct store ----
  #pragma unroll
  for (int nt = 0; nt < 4; ++nt) {
    const int d = nt * 16 + lrow;
    #pragma unroll
    for (int r = 0; r < 4; ++r) {
      const size_t o = ((size_t)b * SEQ + qtile * 64 + qloc + r) * DK + d;
      outR[o] = accR[nt][r];
      outP[o] = accP[nt][r];
    }
  }
}

extern "C" void kernel_launch(void* const* d_in, const int* in_sizes, int n_in,
                              void* d_out, int out_size, void* d_ws, size_t ws_size,
                              hipStream_t stream)
{
  const float* qr = (const float*)d_in[0];
  const float* kr = (const float*)d_in[1];
  const float* vr = (const float*)d_in[2];
  const float* qp = (const float*)d_in[3];
  const float* kp = (const float*)d_in[4];
  const float* vp = (const float*)d_in[5];
  float* out = (float*)d_out;

  // ws: [kv bf16 tiles 16MB][qb bf16 8MB][wsums 1MB]
  unsigned short* kv = (unsigned short*)d_ws;
  unsigned short* qb = (unsigned short*)((char*)d_ws + (16u << 20));
  float* wsums = (float*)((char*)d_ws + (24u << 20));

  const unsigned qblocks = (unsigned)(2 * MAT / 8 / 256);
  ck_prep<<<BATCH * 32 + qblocks, 256, 0, stream>>>(kr, kp, vr, vp, qr, qp, kv, qb);
  ck_sums<<<4 * 32 * BATCH, 256, 0, stream>>>(qb, kv, wsums);
  ck_main<<<32 * BATCH, 256, 0, stream>>>(qb, kv, wsums, out);
}